// Round 17
// baseline (54.318 us; speedup 1.0000x reference)
//
#include <hip/hip_runtime.h>

#define NLAT  256
#define NLON  512
#define LMAXX 128
#define MMAXX 128
#define NV    64
#define NBTE  4   // B*T*E = 2*2*1

typedef __attribute__((ext_vector_type(8))) short bf16x8;
typedef __attribute__((ext_vector_type(4))) short bf16x4;
typedef __attribute__((ext_vector_type(4))) float f32x4;

// round-to-nearest-even float -> bf16
__device__ __forceinline__ unsigned int f2bf(float x) {
    union { float f; unsigned int u; } a; a.f = x;
    return (a.u + 0x7fffu + ((a.u >> 16) & 1u)) >> 16;
}

// ---------------------------------------------------------------------------
// init_tables (fused): blocks 0..511 build tsw, 512..2559 build wt.
// tsw[((ks*16 + mt)*64 + l)*8 + i] = T[mt*16+(l&15)][ks*32+(l>>4)*8+i]
//   T[row][n]: row<128 -> cos(2*pi*row*n/512), row>=128 -> -sin.
// wt[((m*8 + ks)*8 + mt)*512 + lane*8 + i] = leg*qw fragment-packed per m.
// ---------------------------------------------------------------------------
__global__ __launch_bounds__(256) void init_tables(const float* __restrict__ leg,
                                                   const float* __restrict__ qw,
                                                   unsigned short* __restrict__ tsw,
                                                   unsigned short* __restrict__ wt) {
    const int bid = blockIdx.x;
    const int t   = threadIdx.x;
    if (bid < 512) {
        const int gid = bid * 256 + t;                // 131072
        const int i  = gid & 7;
        const int l  = (gid >> 3) & 63;
        const int mt = (gid >> 9) & 15;
        const int ks = gid >> 13;
        const int row = mt * 16 + (l & 15);
        const int n   = ks * 32 + (l >> 4) * 8 + i;
        const int m   = row & 127;
        float s, c;
        sincosf((6.28318530717958647692f / NLON) * (float)((m * n) & (NLON - 1)), &s, &c);
        tsw[gid] = (unsigned short)f2bf((row < 128) ? c : -s);
    } else {
        const int gid  = (bid - 512) * 256 + t;       // 524288
        const int lane = gid & 63;
        const int mt   = (gid >> 6) & 7;
        const int ks   = (gid >> 9) & 7;
        const int m    = gid >> 12;
        const int lr   = mt * 16 + (lane & 15);
        const int k0   = ks * 32 + (lane >> 4) * 8;
        const float* lp = leg + ((size_t)lr * MMAXX + m) * NLAT + k0;
        const float4 p0 = *(const float4*)lp;
        const float4 p1 = *(const float4*)(lp + 4);
        const float4 q0 = *(const float4*)(qw + k0);
        const float4 q1 = *(const float4*)(qw + k0 + 4);
        bf16x8 r;
        r[0] = (short)f2bf(p0.x * q0.x);
        r[1] = (short)f2bf(p0.y * q0.y);
        r[2] = (short)f2bf(p0.z * q0.z);
        r[3] = (short)f2bf(p0.w * q0.w);
        r[4] = (short)f2bf(p1.x * q1.x);
        r[5] = (short)f2bf(p1.y * q1.y);
        r[6] = (short)f2bf(p1.z * q1.z);
        r[7] = (short)f2bf(p1.w * q1.w);
        *(bf16x8*)(wt + (size_t)gid * 8) = r;
    }
}

// ---------------------------------------------------------------------------
// dft_mfma v4 (r14/r16-proven): 1 lat-row/block (grid 1024), 4 waves =
// m-quarters (4 mt each, all 64 v). 64-n chunks (16 scalar staging loads per
// thread), dbuf LDS, issue-early/write-late.
// F output BF16 planar [bte][m][lat][cpl*64+v].
// ---------------------------------------------------------------------------
__global__ __launch_bounds__(256, 3) void dft_mfma(const float* __restrict__ data,
                                                   const unsigned short* __restrict__ tsw,
                                                   unsigned short* __restrict__ F) {
    __shared__ unsigned short xs[2][64][72];   // [buf][v][n+pad], 18.4 KB
    const int t = threadIdx.x;
    const int l = t & 63;
    const int q = t >> 6;              // wave = m quarter (mt = q*4 .. q*4+3)
    const int row = blockIdx.x;        // bte*NLAT + lat
    const int vv = t & 63;             // staging: v
    const int ng = t >> 6;             // staging: 16-n subgroup

    f32x4 acc[4][4];
    #pragma unroll
    for (int mt = 0; mt < 4; ++mt)
        #pragma unroll
        for (int vt = 0; vt < 4; ++vt) acc[mt][vt] = (f32x4){0.f, 0.f, 0.f, 0.f};

    const float* Xb = data + (size_t)row * NLON * NV + vv;

    float xr[16];
    // prologue: chunk 0
    #pragma unroll
    for (int g = 0; g < 16; ++g) xr[g] = Xb[(size_t)(ng * 16 + g) * NV];
    #pragma unroll
    for (int g4 = 0; g4 < 4; ++g4) {
        bf16x4 pk;
        pk.x = (short)f2bf(xr[g4 * 4 + 0]);
        pk.y = (short)f2bf(xr[g4 * 4 + 1]);
        pk.z = (short)f2bf(xr[g4 * 4 + 2]);
        pk.w = (short)f2bf(xr[g4 * 4 + 3]);
        *(bf16x4*)&xs[0][vv][ng * 16 + g4 * 4] = pk;
    }
    __syncthreads();

    #pragma unroll
    for (int ch = 0; ch < 8; ++ch) {   // 64-n chunks
        const int cur = ch & 1;
        if (ch < 7) {                  // issue next chunk's loads early
            #pragma unroll
            for (int g = 0; g < 16; ++g)
                xr[g] = Xb[(size_t)((ch + 1) * 64 + ng * 16 + g) * NV];
        }
        #pragma unroll
        for (int ksl = 0; ksl < 2; ++ksl) {
            const int ks = ch * 2 + ksl;
            bf16x8 b[4];
            #pragma unroll
            for (int vt = 0; vt < 4; ++vt)
                b[vt] = *(const bf16x8*)&xs[cur][vt * 16 + (l & 15)][ksl * 32 + (l >> 4) * 8];
            const unsigned short* ap = tsw + ((size_t)ks * 16 + q * 4) * 512 + l * 8;
            #pragma unroll
            for (int mt = 0; mt < 4; ++mt) {
                const bf16x8 a = *(const bf16x8*)(ap + (size_t)mt * 512);
                #pragma unroll
                for (int vt = 0; vt < 4; ++vt)
                    acc[mt][vt] = __builtin_amdgcn_mfma_f32_16x16x32_bf16(a, b[vt], acc[mt][vt], 0, 0, 0);
            }
        }
        if (ch < 7) {                  // convert + write-late into other buffer
            #pragma unroll
            for (int g4 = 0; g4 < 4; ++g4) {
                bf16x4 pk;
                pk.x = (short)f2bf(xr[g4 * 4 + 0]);
                pk.y = (short)f2bf(xr[g4 * 4 + 1]);
                pk.z = (short)f2bf(xr[g4 * 4 + 2]);
                pk.w = (short)f2bf(xr[g4 * 4 + 3]);
                *(bf16x4*)&xs[cur ^ 1][vv][ng * 16 + g4 * 4] = pk;
            }
        }
        __syncthreads();
    }

    // epilogue: D[r256 = (q*4+mt)*16 + (l>>4)*4 + j][col = vt*16 + (l&15)]
    const int bte = row >> 8, lat = row & (NLAT - 1);
    const int g4i = (l >> 4) * 4;
    #pragma unroll
    for (int mt = 0; mt < 4; ++mt) {
        #pragma unroll
        for (int j = 0; j < 4; ++j) {
            const int r256 = (q * 4 + mt) * 16 + g4i + j;
            const int m    = r256 & 127;
            const int cpl  = r256 >> 7;            // 0 = re, 1 = im
            unsigned short* dp = F + ((size_t)(bte * MMAXX + m) * NLAT + lat) * (NV * 2) + cpl * 64;
            #pragma unroll
            for (int vt = 0; vt < 4; ++vt)
                dp[vt * 16 + (l & 15)] = (unsigned short)f2bf(acc[mt][vt][j]);
        }
    }
}

// ---------------------------------------------------------------------------
// leg_mfma v2: grid 1024 = (m, bte, l-half). Each block: 64 l rows, wave =
// one 16-row l-tile (mtg = lh*4 + w). Whole-block zero fast path when all
// 64 rows are in W's zero triangle (l < m); per-wave skip otherwise.
// XCD-chunked remap keeps each XCD on 16 consecutive m (wt L2-resident).
// ---------------------------------------------------------------------------
__global__ __launch_bounds__(256, 2) void leg_mfma(const unsigned short* __restrict__ F,
                                                   const unsigned short* __restrict__ wt,
                                                   unsigned int* __restrict__ outu) {
    __shared__ unsigned short fs[2][128][40];  // [buf][c][k-slots+pad], 20.5 KB
    const int bid = blockIdx.x;                // 1024 blocks
    const int p   = (bid & 7) * 128 + (bid >> 3);   // XCD-chunked remap (8 x 128)
    const int m   = p >> 3;
    const int bte = (p >> 1) & 3;
    const int lh  = p & 1;                     // l half: rows lh*64 .. lh*64+63
    const int t = threadIdx.x;
    const int l = t & 63;
    const int w = t >> 6;
    const int mtg   = lh * 4 + w;              // global 16-row l-tile index
    const bool wskip = (mtg * 16 + 16) <= m;   // wave tile fully in zero triangle
    const bool bskip = (lh * 64 + 64) <= m;    // whole block in zero triangle

    const unsigned short* Fb = F + (size_t)(bte * MMAXX + m) * NLAT * (NV * 2);
    const unsigned short* wb = wt + (size_t)m * 64 * 512 + l * 8;

    const int kk = t >> 4;             // staging k (0..15; +16 second half)
    const int c8 = (t & 15) * 8;       // staging c base

    f32x4 acc[8];
    #pragma unroll
    for (int j = 0; j < 8; ++j) acc[j] = (f32x4){0.f, 0.f, 0.f, 0.f};

    if (!bskip) {
        // prologue: stage k-chunk 0
        {
            const bf16x8 s0 = *(const bf16x8*)(Fb + (size_t)kk * 128 + c8);
            const bf16x8 s1 = *(const bf16x8*)(Fb + (size_t)(16 + kk) * 128 + c8);
            #pragma unroll
            for (int e = 0; e < 8; ++e) {
                const int c = c8 + e;
                fs[0][c][(((kk >> 3) + (c >> 3)) & 3) * 8 + (kk & 7)]        = (unsigned short)s0[e];
                fs[0][c][((((16 + kk) >> 3) + (c >> 3)) & 3) * 8 + (kk & 7)] = (unsigned short)s1[e];
            }
        }
        __syncthreads();

        #pragma unroll
        for (int ks = 0; ks < 8; ++ks) {
            const int cur = ks & 1;
            bf16x8 s0, s1;
            if (ks < 7) {              // issue next k-chunk loads early
                s0 = *(const bf16x8*)(Fb + ((size_t)(ks + 1) * 32 + kk) * 128 + c8);
                s1 = *(const bf16x8*)(Fb + ((size_t)(ks + 1) * 32 + 16 + kk) * 128 + c8);
            }
            if (!wskip) {
                bf16x8 bq[8];
                #pragma unroll
                for (int nt = 0; nt < 8; ++nt) {
                    const int c = nt * 16 + (l & 15);
                    bq[nt] = *(const bf16x8*)&fs[cur][c][(((l >> 4) + (c >> 3)) & 3) * 8];
                }
                const bf16x8 a = *(const bf16x8*)(wb + ((size_t)ks * 8 + mtg) * 512);
                #pragma unroll
                for (int nt = 0; nt < 8; ++nt)
                    acc[nt] = __builtin_amdgcn_mfma_f32_16x16x32_bf16(a, bq[nt], acc[nt], 0, 0, 0);
            }
            if (ks < 7) {              // write-late into other buffer
                #pragma unroll
                for (int e = 0; e < 8; ++e) {
                    const int c = c8 + e;
                    fs[cur ^ 1][c][(((kk >> 3) + (c >> 3)) & 3) * 8 + (kk & 7)]        = (unsigned short)s0[e];
                    fs[cur ^ 1][c][((((16 + kk) >> 3) + (c >> 3)) & 3) * 8 + (kk & 7)] = (unsigned short)s1[e];
                }
            }
            __syncthreads();
        }
    }

    // epilogue: (l_out = mtg*16 + (l>>4)*4 + j, c = nt*16+(l&15))
    // c<64 -> re(v=c), c>=64 -> im(v=c-64); u32 = im | re<<16.
    const int lr = mtg * 16 + (l >> 4) * 4;
    #pragma unroll
    for (int j = 0; j < 4; ++j) {
        unsigned int* op = outu + ((size_t)(bte * LMAXX + lr + j) * MMAXX + m) * 64 + (l & 15);
        #pragma unroll
        for (int nt = 0; nt < 4; ++nt)
            op[nt * 16] = f2bf(acc[nt + 4][j]) | (f2bf(acc[nt][j]) << 16);
    }
}

extern "C" void kernel_launch(void* const* d_in, const int* in_sizes, int n_in,
                              void* d_out, int out_size, void* d_ws, size_t ws_size,
                              hipStream_t stream) {
    const float* data = (const float*)d_in[0];    // [4][256][512][64] fp32
    const float* leg  = (const float*)d_in[1];    // [128][128][256] fp32
    const float* qw   = (const float*)d_in[2];    // [256] fp32
    unsigned int* outu = (unsigned int*)d_out;    // bf16 [4][128][128][64][(im,re)]

    // ws layout: tsw 256 KB | wt 8.39 MB | F(bf16) 33.6 MB
    unsigned short* tsw = (unsigned short*)d_ws;
    unsigned short* wt  = tsw + 131072;
    unsigned short* F   = wt + (size_t)4194304;

    init_tables<<<dim3(2560), 256, 0, stream>>>(leg, qw, tsw, wt);
    dft_mfma<<<dim3(NBTE * NLAT), 256, 0, stream>>>(data, tsw, F);
    leg_mfma<<<dim3(1024), 256, 0, stream>>>(F, wt, outu);
}

// Round 18
// 49.781 us; speedup vs baseline: 1.0911x; 1.0911x over previous
//
#include <hip/hip_runtime.h>

#define NLAT  256
#define NLON  512
#define LMAXX 128
#define MMAXX 128
#define NV    64
#define NBTE  4   // B*T*E = 2*2*1

typedef __attribute__((ext_vector_type(8))) short bf16x8;
typedef __attribute__((ext_vector_type(4))) short bf16x4;
typedef __attribute__((ext_vector_type(4))) float f32x4;

// round-to-nearest-even float -> bf16
__device__ __forceinline__ unsigned int f2bf(float x) {
    union { float f; unsigned int u; } a; a.f = x;
    return (a.u + 0x7fffu + ((a.u >> 16) & 1u)) >> 16;
}

// ---------------------------------------------------------------------------
// init_tables (fused): blocks 0..511 build tsw, 512..2559 build wt.
// tsw[((ks*16 + mt)*64 + l)*8 + i] = T[mt*16+(l&15)][ks*32+(l>>4)*8+i]
//   T[row][n]: row<128 -> cos(2*pi*row*n/512), row>=128 -> -sin.
// wt[((m*8 + ks)*8 + mt)*512 + lane*8 + i] = leg*qw fragment-packed per m.
// ---------------------------------------------------------------------------
__global__ __launch_bounds__(256) void init_tables(const float* __restrict__ leg,
                                                   const float* __restrict__ qw,
                                                   unsigned short* __restrict__ tsw,
                                                   unsigned short* __restrict__ wt) {
    const int bid = blockIdx.x;
    const int t   = threadIdx.x;
    if (bid < 512) {
        const int gid = bid * 256 + t;                // 131072
        const int i  = gid & 7;
        const int l  = (gid >> 3) & 63;
        const int mt = (gid >> 9) & 15;
        const int ks = gid >> 13;
        const int row = mt * 16 + (l & 15);
        const int n   = ks * 32 + (l >> 4) * 8 + i;
        const int m   = row & 127;
        float s, c;
        sincosf((6.28318530717958647692f / NLON) * (float)((m * n) & (NLON - 1)), &s, &c);
        tsw[gid] = (unsigned short)f2bf((row < 128) ? c : -s);
    } else {
        const int gid  = (bid - 512) * 256 + t;       // 524288
        const int lane = gid & 63;
        const int mt   = (gid >> 6) & 7;
        const int ks   = (gid >> 9) & 7;
        const int m    = gid >> 12;
        const int lr   = mt * 16 + (lane & 15);
        const int k0   = ks * 32 + (lane >> 4) * 8;
        const float* lp = leg + ((size_t)lr * MMAXX + m) * NLAT + k0;
        const float4 p0 = *(const float4*)lp;
        const float4 p1 = *(const float4*)(lp + 4);
        const float4 q0 = *(const float4*)(qw + k0);
        const float4 q1 = *(const float4*)(qw + k0 + 4);
        bf16x8 r;
        r[0] = (short)f2bf(p0.x * q0.x);
        r[1] = (short)f2bf(p0.y * q0.y);
        r[2] = (short)f2bf(p0.z * q0.z);
        r[3] = (short)f2bf(p0.w * q0.w);
        r[4] = (short)f2bf(p1.x * q1.x);
        r[5] = (short)f2bf(p1.y * q1.y);
        r[6] = (short)f2bf(p1.z * q1.z);
        r[7] = (short)f2bf(p1.w * q1.w);
        *(bf16x8*)(wt + (size_t)gid * 8) = r;
    }
}

// ---------------------------------------------------------------------------
// dft_mfma v4 (r14/r16-proven): 1 lat-row/block (grid 1024), 4 waves =
// m-quarters (4 mt each, all 64 v). 64-n chunks (16 scalar staging loads per
// thread), dbuf LDS, issue-early/write-late.
// F output BF16 planar [bte][m][lat][cpl*64+v].
// ---------------------------------------------------------------------------
__global__ __launch_bounds__(256, 3) void dft_mfma(const float* __restrict__ data,
                                                   const unsigned short* __restrict__ tsw,
                                                   unsigned short* __restrict__ F) {
    __shared__ unsigned short xs[2][64][72];   // [buf][v][n+pad], 18.4 KB
    const int t = threadIdx.x;
    const int l = t & 63;
    const int q = t >> 6;              // wave = m quarter (mt = q*4 .. q*4+3)
    const int row = blockIdx.x;        // bte*NLAT + lat
    const int vv = t & 63;             // staging: v
    const int ng = t >> 6;             // staging: 16-n subgroup

    f32x4 acc[4][4];
    #pragma unroll
    for (int mt = 0; mt < 4; ++mt)
        #pragma unroll
        for (int vt = 0; vt < 4; ++vt) acc[mt][vt] = (f32x4){0.f, 0.f, 0.f, 0.f};

    const float* Xb = data + (size_t)row * NLON * NV + vv;

    float xr[16];
    // prologue: chunk 0
    #pragma unroll
    for (int g = 0; g < 16; ++g) xr[g] = Xb[(size_t)(ng * 16 + g) * NV];
    #pragma unroll
    for (int g4 = 0; g4 < 4; ++g4) {
        bf16x4 pk;
        pk.x = (short)f2bf(xr[g4 * 4 + 0]);
        pk.y = (short)f2bf(xr[g4 * 4 + 1]);
        pk.z = (short)f2bf(xr[g4 * 4 + 2]);
        pk.w = (short)f2bf(xr[g4 * 4 + 3]);
        *(bf16x4*)&xs[0][vv][ng * 16 + g4 * 4] = pk;
    }
    __syncthreads();

    #pragma unroll
    for (int ch = 0; ch < 8; ++ch) {   // 64-n chunks
        const int cur = ch & 1;
        if (ch < 7) {                  // issue next chunk's loads early
            #pragma unroll
            for (int g = 0; g < 16; ++g)
                xr[g] = Xb[(size_t)((ch + 1) * 64 + ng * 16 + g) * NV];
        }
        #pragma unroll
        for (int ksl = 0; ksl < 2; ++ksl) {
            const int ks = ch * 2 + ksl;
            bf16x8 b[4];
            #pragma unroll
            for (int vt = 0; vt < 4; ++vt)
                b[vt] = *(const bf16x8*)&xs[cur][vt * 16 + (l & 15)][ksl * 32 + (l >> 4) * 8];
            const unsigned short* ap = tsw + ((size_t)ks * 16 + q * 4) * 512 + l * 8;
            #pragma unroll
            for (int mt = 0; mt < 4; ++mt) {
                const bf16x8 a = *(const bf16x8*)(ap + (size_t)mt * 512);
                #pragma unroll
                for (int vt = 0; vt < 4; ++vt)
                    acc[mt][vt] = __builtin_amdgcn_mfma_f32_16x16x32_bf16(a, b[vt], acc[mt][vt], 0, 0, 0);
            }
        }
        if (ch < 7) {                  // convert + write-late into other buffer
            #pragma unroll
            for (int g4 = 0; g4 < 4; ++g4) {
                bf16x4 pk;
                pk.x = (short)f2bf(xr[g4 * 4 + 0]);
                pk.y = (short)f2bf(xr[g4 * 4 + 1]);
                pk.z = (short)f2bf(xr[g4 * 4 + 2]);
                pk.w = (short)f2bf(xr[g4 * 4 + 3]);
                *(bf16x4*)&xs[cur ^ 1][vv][ng * 16 + g4 * 4] = pk;
            }
        }
        __syncthreads();
    }

    // epilogue: D[r256 = (q*4+mt)*16 + (l>>4)*4 + j][col = vt*16 + (l&15)]
    const int bte = row >> 8, lat = row & (NLAT - 1);
    const int g4i = (l >> 4) * 4;
    #pragma unroll
    for (int mt = 0; mt < 4; ++mt) {
        #pragma unroll
        for (int j = 0; j < 4; ++j) {
            const int r256 = (q * 4 + mt) * 16 + g4i + j;
            const int m    = r256 & 127;
            const int cpl  = r256 >> 7;            // 0 = re, 1 = im
            unsigned short* dp = F + ((size_t)(bte * MMAXX + m) * NLAT + lat) * (NV * 2) + cpl * 64;
            #pragma unroll
            for (int vt = 0; vt < 4; ++vt)
                dp[vt * 16 + (l & 15)] = (unsigned short)f2bf(acc[mt][vt][j]);
        }
    }
}

// ---------------------------------------------------------------------------
// leg_mfma (r16-proven): per (bte,m) GEMM
//   C[128 l][128 c] = W[128 l][256 k] x F[256 k][128 c]
// bf16 MFMA, fp32 accum. XCD-swizzled block order (16 consecutive m per XCD ->
// wt L2-resident). Waves whose 32 l-rows are all < m skip compute (W zero
// triangle) -- acc stays 0, stores unchanged.
// ---------------------------------------------------------------------------
__global__ __launch_bounds__(256, 2) void leg_mfma(const unsigned short* __restrict__ F,
                                                   const unsigned short* __restrict__ wt,
                                                   unsigned int* __restrict__ outu) {
    __shared__ unsigned short fs[2][128][40];  // [buf][c][k-slots+pad], 20.5 KB
    const int bid = blockIdx.x;                // 512 blocks
    const int p   = ((bid & 7) << 6) | (bid >> 3);   // XCD-chunked remap
    const int m   = p >> 2;
    const int bte = p & 3;
    const int t = threadIdx.x;
    const int l = t & 63;
    const int w = t >> 6;              // wave: l-rows [w*32, w*32+32)
    const bool skip = (w * 32 + 32) <= m;   // entire wave in zero triangle

    const unsigned short* Fb = F + (size_t)(bte * MMAXX + m) * NLAT * (NV * 2);
    const unsigned short* wb = wt + (size_t)m * 64 * 512 + l * 8;

    const int kk = t >> 4;             // staging k (0..15; +16 second half)
    const int c8 = (t & 15) * 8;       // staging c base

    f32x4 acc[2][8];
    #pragma unroll
    for (int i = 0; i < 2; ++i)
        #pragma unroll
        for (int j = 0; j < 8; ++j) acc[i][j] = (f32x4){0.f, 0.f, 0.f, 0.f};

    // prologue: stage k-chunk 0
    {
        const bf16x8 s0 = *(const bf16x8*)(Fb + (size_t)kk * 128 + c8);
        const bf16x8 s1 = *(const bf16x8*)(Fb + (size_t)(16 + kk) * 128 + c8);
        #pragma unroll
        for (int e = 0; e < 8; ++e) {
            const int c = c8 + e;
            fs[0][c][(((kk >> 3) + (c >> 3)) & 3) * 8 + (kk & 7)]        = (unsigned short)s0[e];
            fs[0][c][((((16 + kk) >> 3) + (c >> 3)) & 3) * 8 + (kk & 7)] = (unsigned short)s1[e];
        }
    }
    __syncthreads();

    #pragma unroll
    for (int ks = 0; ks < 8; ++ks) {
        const int cur = ks & 1;
        bf16x8 s0, s1;
        if (ks < 7) {                  // issue next k-chunk loads early
            s0 = *(const bf16x8*)(Fb + ((size_t)(ks + 1) * 32 + kk) * 128 + c8);
            s1 = *(const bf16x8*)(Fb + ((size_t)(ks + 1) * 32 + 16 + kk) * 128 + c8);
        }
        if (!skip) {
            bf16x8 bq[8];
            #pragma unroll
            for (int nt = 0; nt < 8; ++nt) {
                const int c = nt * 16 + (l & 15);
                bq[nt] = *(const bf16x8*)&fs[cur][c][(((l >> 4) + (c >> 3)) & 3) * 8];
            }
            #pragma unroll
            for (int mt2 = 0; mt2 < 2; ++mt2) {
                const bf16x8 a = *(const bf16x8*)(wb + ((size_t)ks * 8 + w * 2 + mt2) * 512);
                #pragma unroll
                for (int nt = 0; nt < 8; ++nt)
                    acc[mt2][nt] = __builtin_amdgcn_mfma_f32_16x16x32_bf16(a, bq[nt], acc[mt2][nt], 0, 0, 0);
            }
        }
        if (ks < 7) {                  // write-late into other buffer
            #pragma unroll
            for (int e = 0; e < 8; ++e) {
                const int c = c8 + e;
                fs[cur ^ 1][c][(((kk >> 3) + (c >> 3)) & 3) * 8 + (kk & 7)]        = (unsigned short)s0[e];
                fs[cur ^ 1][c][((((16 + kk) >> 3) + (c >> 3)) & 3) * 8 + (kk & 7)] = (unsigned short)s1[e];
            }
        }
        __syncthreads();
    }

    // epilogue: (l_out = (w*2+mt2)*16 + (l>>4)*4 + j, c = nt*16+(l&15))
    // c<64 -> re(v=c), c>=64 -> im(v=c-64); u32 = im | re<<16.
    #pragma unroll
    for (int mt2 = 0; mt2 < 2; ++mt2) {
        const int lr = (w * 2 + mt2) * 16 + (l >> 4) * 4;
        #pragma unroll
        for (int j = 0; j < 4; ++j) {
            unsigned int* op = outu + ((size_t)(bte * LMAXX + lr + j) * MMAXX + m) * 64 + (l & 15);
            #pragma unroll
            for (int nt = 0; nt < 4; ++nt)
                op[nt * 16] = f2bf(acc[mt2][nt + 4][j]) | (f2bf(acc[mt2][nt][j]) << 16);
        }
    }
}

extern "C" void kernel_launch(void* const* d_in, const int* in_sizes, int n_in,
                              void* d_out, int out_size, void* d_ws, size_t ws_size,
                              hipStream_t stream) {
    const float* data = (const float*)d_in[0];    // [4][256][512][64] fp32
    const float* leg  = (const float*)d_in[1];    // [128][128][256] fp32
    const float* qw   = (const float*)d_in[2];    // [256] fp32
    unsigned int* outu = (unsigned int*)d_out;    // bf16 [4][128][128][64][(im,re)]

    // ws layout: tsw 256 KB | wt 8.39 MB | F(bf16) 33.6 MB
    unsigned short* tsw = (unsigned short*)d_ws;
    unsigned short* wt  = tsw + 131072;
    unsigned short* F   = wt + (size_t)4194304;

    init_tables<<<dim3(2560), 256, 0, stream>>>(leg, qw, tsw, wt);
    dft_mfma<<<dim3(NBTE * NLAT), 256, 0, stream>>>(data, tsw, F);
    leg_mfma<<<dim3(512), 256, 0, stream>>>(F, wt, outu);
}